// Round 3
// baseline (26.754 us; speedup 1.0000x reference)
//
#include <hip/hip_runtime.h>

// ESN scan: out[b,c,t,r] = s_t, s_t = tanh(x[b,c,t]*w[r] + s_{t-1}*d[r]).
// B=32 C=8 T=512 R=256. One block per (b,c), one thread per r-chain.
//
// R1: x staged in LDS (no global loads in loop -> stores never vmcnt-waited).
// R2: (a) carried chain shortened to {fma,exp2,add,rcp}: next earg computed
//     directly from rc (earg' = pre' + m2dk*rc, pre' off-chain); the stored
//     s = fma(-2,rc,1) is off-chain too. (b) unroll 8 -> store-source WAR
//     (expcnt) slack doubled so HBM backpressure doesn't re-couple the chain.

constexpr int Bdim = 32;
constexpr int Cdim = 8;
constexpr int Tdim = 512;
constexpr int Rdim = 256;
constexpr int T4   = Tdim / 4;   // 128 float4 per row

__device__ __forceinline__ float fast_exp2(float v) {
#if defined(__has_builtin)
#if __has_builtin(__builtin_amdgcn_exp2f)
    return __builtin_amdgcn_exp2f(v);
#else
    return exp2f(v);
#endif
#else
    return exp2f(v);
#endif
}

__global__ __launch_bounds__(256, 1) void esn_scan_kernel(
    const float* __restrict__ x,     // [B*C, T]
    const float* __restrict__ W_in,  // [R] (R,1 flattened)
    const float* __restrict__ d,     // [R]
    float* __restrict__ out)         // [B*C, T, R]
{
    const int bc = blockIdx.x;
    const int r  = threadIdx.x;

    // tanh(a) = 1 - 2/(exp2(K*a)+1), K = 2*log2(e). Fold K into w,d.
    const float K    = 2.0f * 1.4426950408889634f;
    const float wk   = W_in[r] * K;
    const float dk   = d[r] * K;
    const float m2dk = -2.0f * dk;

    __shared__ float4 xs4[T4];   // 2 KiB
    {
        const float4* __restrict__ x4 = reinterpret_cast<const float4*>(x + bc * Tdim);
        if (threadIdx.x < T4) xs4[threadIdx.x] = x4[threadIdx.x];
    }
    __syncthreads();

    float* __restrict__ o = out + (size_t)bc * Tdim * Rdim + r;

    // Group = 8 time steps = 2 float4 of x. Double-buffer groups in regs.
    float4 a0 = xs4[0], a1 = xs4[1];   // group g   (t = 8g .. 8g+7)
    float4 b0 = xs4[2], b1 = xs4[3];   // group g+1

    float earg = a0.x * wk;            // t=0 argument (s_init = 0)

    #pragma unroll 1
    for (int g = 0; g < Tdim / 8; ++g) {
        // Prefetch group g+2 (clamped; tail values unused).
        const int pf = (2 * g + 4 < T4 - 1) ? (2 * g + 4) : (T4 - 2);
        float4 c0 = xs4[pf], c1 = xs4[pf + 1];

        // Off-chain: pre_j = x_{t+1}*wk + dk for each step's successor arg.
        float pre0 = fmaf(a0.y, wk, dk);
        float pre1 = fmaf(a0.z, wk, dk);
        float pre2 = fmaf(a0.w, wk, dk);
        float pre3 = fmaf(a1.x, wk, dk);
        float pre4 = fmaf(a1.y, wk, dk);
        float pre5 = fmaf(a1.z, wk, dk);
        float pre6 = fmaf(a1.w, wk, dk);
        float pre7 = fmaf(b0.x, wk, dk);   // last group's pre7 feeds a dead earg

        float* ob  = o + (size_t)(g * 8) * Rdim;        // steps 0..3
        float* ob4 = ob + (size_t)4 * Rdim;             // steps 4..7 (keeps
                                                        // imm offsets < 4096B)
        {   float e  = fast_exp2(earg);
            float rc = __builtin_amdgcn_rcpf(e + 1.0f);
            ob[0 * Rdim] = fmaf(-2.0f, rc, 1.0f);
            earg = fmaf(m2dk, rc, pre0);
        }
        {   float e  = fast_exp2(earg);
            float rc = __builtin_amdgcn_rcpf(e + 1.0f);
            ob[1 * Rdim] = fmaf(-2.0f, rc, 1.0f);
            earg = fmaf(m2dk, rc, pre1);
        }
        {   float e  = fast_exp2(earg);
            float rc = __builtin_amdgcn_rcpf(e + 1.0f);
            ob[2 * Rdim] = fmaf(-2.0f, rc, 1.0f);
            earg = fmaf(m2dk, rc, pre2);
        }
        {   float e  = fast_exp2(earg);
            float rc = __builtin_amdgcn_rcpf(e + 1.0f);
            ob[3 * Rdim] = fmaf(-2.0f, rc, 1.0f);
            earg = fmaf(m2dk, rc, pre3);
        }
        {   float e  = fast_exp2(earg);
            float rc = __builtin_amdgcn_rcpf(e + 1.0f);
            ob4[0 * Rdim] = fmaf(-2.0f, rc, 1.0f);
            earg = fmaf(m2dk, rc, pre4);
        }
        {   float e  = fast_exp2(earg);
            float rc = __builtin_amdgcn_rcpf(e + 1.0f);
            ob4[1 * Rdim] = fmaf(-2.0f, rc, 1.0f);
            earg = fmaf(m2dk, rc, pre5);
        }
        {   float e  = fast_exp2(earg);
            float rc = __builtin_amdgcn_rcpf(e + 1.0f);
            ob4[2 * Rdim] = fmaf(-2.0f, rc, 1.0f);
            earg = fmaf(m2dk, rc, pre6);
        }
        {   float e  = fast_exp2(earg);
            float rc = __builtin_amdgcn_rcpf(e + 1.0f);
            ob4[3 * Rdim] = fmaf(-2.0f, rc, 1.0f);
            earg = fmaf(m2dk, rc, pre7);
        }

        a0 = b0; a1 = b1;
        b0 = c0; b1 = c1;
    }
}

extern "C" void kernel_launch(void* const* d_in, const int* in_sizes, int n_in,
                              void* d_out, int out_size, void* d_ws, size_t ws_size,
                              hipStream_t stream) {
    const float* x    = (const float*)d_in[0];  // [B,C,T]
    const float* W_in = (const float*)d_in[1];  // [R,1]
    const float* d    = (const float*)d_in[2];  // [R]
    float* out        = (float*)d_out;          // [B,C,T,R]

    dim3 grid(Bdim * Cdim);
    dim3 block(Rdim);
    esn_scan_kernel<<<grid, block, 0, stream>>>(x, W_in, d, out);
}